// Round 6
// baseline (1008.402 us; speedup 1.0000x reference)
//
#include <hip/hip_runtime.h>
#include <hip/hip_bf16.h>

// Problem:
//   primary_caps u : [16, 1152, 8]     fp32 (147456 elems)
//   W              : [10, 1152, 16, 8] fp32 (1474560 elems)
//   B_prior        : [10, 1, 1152]     fp32 (11520 elems)
//   out            : [16, 10, 16]      fp32 (2560 elems) — reference returns
//                    float32; harness rule "else float*". The "(bf16)" in the
//                    test label is generated-fstring text, not the buffer dtype
//                    (rounds 2/3/5 wrote bf16 -> scrambled-fp32 readback ->
//                    the reproducible 1.121094 absmax).
constexpr int BN = 16;    // batch
constexpr int NN = 1152;  // primary caps
constexpr int DP = 8;     // primary dim
constexpr int ND = 10;    // digit caps
constexpr int DD = 16;    // digit dim
constexpr int TPB = 512;  // 8 waves
constexpr int WAVES = TPB / 64;
constexpr int NK = 3;     // ceil(NN/TPB)

// Algebra (exact, not approximate):
//   A_sum[b,d,m] = sum_n U[n]·U[m]/sqrt8 = dot(T, U[m])/sqrt8,  T = sum_n U[n]
//   C[b,d,n]     = softmax over d
//   S[b,d,j]     = sum_n (Bp[d,n] + C[b,d,n]) * U_hat[b,d,n,j]
//   out          = squash(S) per (b,d)
// One block per b; all reductions block-local; d_ws unused.

__device__ __forceinline__ void load8(const float* __restrict__ p, float* dst) {
    const float4 a = reinterpret_cast<const float4*>(p)[0];
    const float4 b = reinterpret_cast<const float4*>(p)[1];
    dst[0] = a.x; dst[1] = a.y; dst[2] = a.z; dst[3] = a.w;
    dst[4] = b.x; dst[5] = b.y; dst[6] = b.z; dst[7] = b.w;
}

__global__ __launch_bounds__(TPB) void caps_fused(
    const float* __restrict__ u,
    const float* __restrict__ W,
    const float* __restrict__ Bp,
    float* __restrict__ out)
{
    const int b = blockIdx.x;
    const int t = threadIdx.x;
    const int wave = t >> 6, lane = t & 63;

    __shared__ float Tall[ND][DD];          // 640 B
    __shared__ float Red[WAVES][ND * DD];   // 5120 B

    // ---------------- Pass 1: T[d][j] = sum_n U_hat[b,d,n,j] ----------------
    float Tl[ND][DD];
#pragma unroll
    for (int d = 0; d < ND; ++d)
#pragma unroll
        for (int j = 0; j < DD; ++j) Tl[d][j] = 0.f;

    for (int k = 0; k < NK; ++k) {
        const int n = t + TPB * k;
        if (n < NN) {
            float uf[DP];
            load8(u + ((size_t)b * NN + n) * DP, uf);
#pragma unroll
            for (int d = 0; d < ND; ++d) {
                const float* wrow = W + ((size_t)d * NN + n) * (DD * DP);
#pragma unroll
                for (int j = 0; j < DD; ++j) {
                    float wf[DP];
                    load8(wrow + j * DP, wf);
                    float acc = 0.f;
#pragma unroll
                    for (int i = 0; i < DP; ++i) acc += wf[i] * uf[i];
                    Tl[d][j] += acc;
                }
            }
        }
    }
#pragma unroll
    for (int d = 0; d < ND; ++d)
#pragma unroll
        for (int j = 0; j < DD; ++j) {
#pragma unroll
            for (int off = 32; off >= 1; off >>= 1)
                Tl[d][j] += __shfl_xor(Tl[d][j], off);
        }
    if (lane == 0) {
#pragma unroll
        for (int d = 0; d < ND; ++d)
#pragma unroll
            for (int j = 0; j < DD; ++j) Red[wave][d * DD + j] = Tl[d][j];
    }
    __syncthreads();
    if (t < ND * DD) {
        float s = 0.f;
#pragma unroll
        for (int w = 0; w < WAVES; ++w) s += Red[w][t];
        Tall[t / DD][t % DD] = s;
    }
    __syncthreads();

    // ---- Pass 2: per n: scores a[q], softmax over q, fused S accumulation ----
    constexpr float RS8 = 0.35355339059327373f;  // 1/sqrt(8)
    float Sl[ND][DD];
#pragma unroll
    for (int d = 0; d < ND; ++d)
#pragma unroll
        for (int j = 0; j < DD; ++j) Sl[d][j] = 0.f;

    for (int k = 0; k < NK; ++k) {
        const int n = t + TPB * k;
        if (n < NN) {
            float uf[DP];
            load8(u + ((size_t)b * NN + n) * DP, uf);
            float a[ND];
#pragma unroll
            for (int q = 0; q < ND; ++q) {
                const float* wrow = W + ((size_t)q * NN + n) * (DD * DP);
                float aq = 0.f;
#pragma unroll
                for (int j = 0; j < DD; ++j) {
                    float wf[DP];
                    load8(wrow + j * DP, wf);
                    float acc = 0.f;
#pragma unroll
                    for (int i = 0; i < DP; ++i) acc += wf[i] * uf[i];
                    aq += Tall[q][j] * acc;
                }
                a[q] = aq * RS8;
            }
            float m = a[0];
#pragma unroll
            for (int q = 1; q < ND; ++q) m = fmaxf(m, a[q]);
            float se = 0.f;
#pragma unroll
            for (int q = 0; q < ND; ++q) se += expf(a[q] - m);
            const float inv_se = 1.f / se;
#pragma unroll
            for (int q = 0; q < ND; ++q) {
                const float wgt = Bp[q * NN + n] + expf(a[q] - m) * inv_se;
                const float* wrow = W + ((size_t)q * NN + n) * (DD * DP);
#pragma unroll
                for (int j = 0; j < DD; ++j) {
                    float wf[DP];
                    load8(wrow + j * DP, wf);
                    float acc = 0.f;
#pragma unroll
                    for (int i = 0; i < DP; ++i) acc += wf[i] * uf[i];
                    Sl[q][j] += wgt * acc;
                }
            }
        }
    }

    // block-reduce S, then fused squash
#pragma unroll
    for (int d = 0; d < ND; ++d)
#pragma unroll
        for (int j = 0; j < DD; ++j) {
#pragma unroll
            for (int off = 32; off >= 1; off >>= 1)
                Sl[d][j] += __shfl_xor(Sl[d][j], off);
        }
    if (lane == 0) {
#pragma unroll
        for (int d = 0; d < ND; ++d)
#pragma unroll
            for (int j = 0; j < DD; ++j) Red[wave][d * DD + j] = Sl[d][j];
    }
    __syncthreads();
    if (t < ND * DD) {
        float Sv = 0.f;
#pragma unroll
        for (int w = 0; w < WAVES; ++w) Sv += Red[w][t];
        float n2 = Sv * Sv;  // t = d*16+j: 16-lane groups are aligned
#pragma unroll
        for (int off = 8; off >= 1; off >>= 1) n2 += __shfl_xor(n2, off, 16);
        const float nrm = sqrtf(n2);
        const float coef = 1.f - 1.f / (expf(nrm) + 1e-7f);
        const float scale = coef / (nrm + 1e-7f);
        out[(size_t)b * (ND * DD) + t] = Sv * scale;  // fp32 store
    }
}

extern "C" void kernel_launch(void* const* d_in, const int* in_sizes, int n_in,
                              void* d_out, int out_size, void* d_ws, size_t ws_size,
                              hipStream_t stream) {
    // Identify inputs by unique element counts (robust to permutation).
    const float* u  = nullptr;   // 147456
    const float* W  = nullptr;   // 1474560
    const float* Bp = nullptr;   // 11520
    for (int i = 0; i < n_in; ++i) {
        const int s = in_sizes[i];
        if (s == BN * NN * DP)            u  = (const float*)d_in[i];
        else if (s == ND * NN * DD * DP)  W  = (const float*)d_in[i];
        else if (s == ND * NN)            Bp = (const float*)d_in[i];
    }
    float* out = (float*)d_out;
    (void)d_ws; (void)ws_size;  // deliberately unused

    caps_fused<<<dim3(BN), TPB, 0, stream>>>(u, W, Bp, out);
}

// Round 7
// 311.029 us; speedup vs baseline: 3.2422x; 3.2422x over previous
//
#include <hip/hip_runtime.h>
#include <hip/hip_bf16.h>

// DigitCaps, fp32 in / fp32 out (settled in rounds 1-6):
//   u  [16,1152,8], W [10,1152,16,8], Bp [10,1,1152], out [16,10,16]
// Algebra (exact): A_sum[b,d,m] = dot(T[b,d,:], U_hat[b,d,m,:])/sqrt8,
//   T = sum_n U_hat;  C = softmax_d(A_sum);  S = sum_n (Bp+C)*U_hat; squash.
// Round-6 lesson: grid=16 was latency-bound (VALUBusy 0.28%, occ 1.5%,
// 90 MB L2-miss from 16x3 full-W passes). Now: W read once per phase for ALL
// b (batch inside the block), 3 kernels at the 2 true sync points, 20 KB ws.
constexpr int BN = 16, NN = 1152, DP = 8, ND = 10, DD = 16;
constexpr int CHA = 72;   // n per block in caps_T   (16 chunks)
constexpr int CHB = 8;    // n per block in caps_S   (144 blocks)

__device__ __forceinline__ void load8(const float* __restrict__ p, float* dst) {
    const float4 a = reinterpret_cast<const float4*>(p)[0];
    const float4 b = reinterpret_cast<const float4*>(p)[1];
    dst[0] = a.x; dst[1] = a.y; dst[2] = a.z; dst[3] = a.w;
    dst[4] = b.x; dst[5] = b.y; dst[6] = b.z; dst[7] = b.w;
}

// ---- Phase A: T[b,d,j] += sum_{n in chunk} W[d,n,j,:]·u[b,n,:] ----
// block = (d, chunk); thread: j = t&15 (coalesced over W row), b = t>>4.
__global__ __launch_bounds__(256) void caps_T(
    const float* __restrict__ u, const float* __restrict__ W,
    float* __restrict__ T)
{
    const int d = blockIdx.x >> 4, c = blockIdx.x & 15;
    const int j = threadIdx.x & 15, b = threadIdx.x >> 4;
    const int n0 = c * CHA;
    float acc = 0.f;
    for (int nn = 0; nn < CHA; ++nn) {
        const int n = n0 + nn;
        float wf[DP], uf[DP];
        load8(W + (((size_t)d * NN + n) * DD + j) * DP, wf);
        load8(u + ((size_t)b * NN + n) * DP, uf);
        float s = 0.f;
#pragma unroll
        for (int i = 0; i < DP; ++i) s += wf[i] * uf[i];
        acc += s;
    }
    atomicAdd(&T[((size_t)b * ND + d) * DD + j], acc);  // 16 adds/cell total
}

// ---- Phase B: scores -> softmax over d -> S accumulation ----
// block = 8 n's; thread t<128: b = t>>3, nn = t&7 (8 n-lanes contiguous).
__global__ __launch_bounds__(128) void caps_S(
    const float* __restrict__ u, const float* __restrict__ W,
    const float* __restrict__ Bp, const float* __restrict__ T,
    float* __restrict__ S)
{
    __shared__ float Tl[BN * ND * DD];  // 10240 B
    const int t = threadIdx.x;
    for (int idx = t; idx < BN * ND * DD; idx += 128) Tl[idx] = T[idx];
    __syncthreads();

    const int b = t >> 3, nn = t & 7;
    const int n = blockIdx.x * CHB + nn;
    constexpr float RS8 = 0.35355339059327373f;  // 1/sqrt(8)

    float uf[DP];
    load8(u + ((size_t)b * NN + n) * DP, uf);

    float a[ND];
#pragma unroll
    for (int q = 0; q < ND; ++q) {
        const float* wrow = W + ((size_t)q * NN + n) * (DD * DP);
        float aq = 0.f;
#pragma unroll
        for (int j = 0; j < DD; ++j) {
            float wf[DP];
            load8(wrow + j * DP, wf);
            float uh = 0.f;
#pragma unroll
            for (int i = 0; i < DP; ++i) uh += wf[i] * uf[i];
            aq += Tl[((size_t)b * ND + q) * DD + j] * uh;
        }
        a[q] = aq * RS8;
    }
    float m = a[0];
#pragma unroll
    for (int q = 1; q < ND; ++q) m = fmaxf(m, a[q]);
    float se = 0.f;
#pragma unroll
    for (int q = 0; q < ND; ++q) se += expf(a[q] - m);
    const float inv_se = 1.f / se;
    float wgt[ND];
#pragma unroll
    for (int q = 0; q < ND; ++q)
        wgt[q] = Bp[q * NN + n] + expf(a[q] - m) * inv_se;

    // second sweep: W rows are L1-hot; reduce over the 8 n-lanes, then one
    // global atomicAdd per (b,q,j) per block (144 adds/cell total).
#pragma unroll
    for (int q = 0; q < ND; ++q) {
        const float* wrow = W + ((size_t)q * NN + n) * (DD * DP);
#pragma unroll
        for (int j = 0; j < DD; ++j) {
            float wf[DP];
            load8(wrow + j * DP, wf);
            float uh = 0.f;
#pragma unroll
            for (int i = 0; i < DP; ++i) uh += wf[i] * uf[i];
            float v = wgt[q] * uh;
            v += __shfl_xor(v, 4, 8);
            v += __shfl_xor(v, 2, 8);
            v += __shfl_xor(v, 1, 8);
            if (nn == 0) atomicAdd(&S[((size_t)b * ND + q) * DD + j], v);
        }
    }
}

// ---- Phase C: squash(S) per (b,d), fp32 store ----
__global__ __launch_bounds__(64) void caps_out(
    const float* __restrict__ S, float* __restrict__ out)
{
    const int bd = blockIdx.x;
    const int lane = threadIdx.x;
    if (lane < DD) {
        const float Sv = S[(size_t)bd * DD + lane];
        float n2 = Sv * Sv;
#pragma unroll
        for (int off = 8; off >= 1; off >>= 1) n2 += __shfl_xor(n2, off, 16);
        const float nrm = sqrtf(n2);
        const float coef = 1.f - 1.f / (expf(nrm) + 1e-7f);
        out[(size_t)bd * DD + lane] = Sv * (coef / (nrm + 1e-7f));
    }
}

extern "C" void kernel_launch(void* const* d_in, const int* in_sizes, int n_in,
                              void* d_out, int out_size, void* d_ws, size_t ws_size,
                              hipStream_t stream) {
    const float* u  = nullptr;   // 147456
    const float* W  = nullptr;   // 1474560
    const float* Bp = nullptr;   // 11520
    for (int i = 0; i < n_in; ++i) {
        const int s = in_sizes[i];
        if (s == BN * NN * DP)            u  = (const float*)d_in[i];
        else if (s == ND * NN * DD * DP)  W  = (const float*)d_in[i];
        else if (s == ND * NN)            Bp = (const float*)d_in[i];
    }
    float* out = (float*)d_out;
    float* T = (float*)d_ws;            // 2560 fp32
    float* S = T + BN * ND * DD;        // 2560 fp32  (ws use: 20 KB total)

    hipMemsetAsync(d_ws, 0, 2 * BN * ND * DD * sizeof(float), stream);
    caps_T  <<<dim3(ND * 16), 256, 0, stream>>>(u, W, T);
    caps_S  <<<dim3(NN / CHB), 128, 0, stream>>>(u, W, Bp, T, S);
    caps_out<<<dim3(BN * ND), 64, 0, stream>>>(S, out);
}

// Round 8
// 94.081 us; speedup vs baseline: 10.7185x; 3.3060x over previous
//
#include <hip/hip_runtime.h>
#include <hip/hip_bf16.h>

// DigitCaps, fp32 in / fp32 out:
//   u [16,1152,8], W [10,1152,16,8], Bp [10,1,1152], out [16,10,16]
// Exact algebra: A_sum[b,d,m] = dot(T[b,d,:], U_hat[b,d,m,:])/sqrt8,
//   T = sum_n U_hat;  C = softmax_d;  S = sum_n (Bp+C)*U_hat;  squash(S).
// Round-7 lesson: caps_S had 320-deep serial load chains at 3% occupancy
// (VALUBusy 0.75%). Now thread=(b,n,j): uh[q] in registers kills the second
// W sweep; 576-block grid gives ~9 waves/CU; load chains are 10-deep.
constexpr int BN = 16, NN = 1152, DP = 8, ND = 10, DD = 16;
constexpr int NCHA = 4;  // n's per block in caps_T -> 288 blocks
constexpr int NCHB = 2;  // n's per block in caps_S -> 576 blocks

__device__ __forceinline__ void load8(const float* __restrict__ p, float* dst) {
    const float4 a = reinterpret_cast<const float4*>(p)[0];
    const float4 b = reinterpret_cast<const float4*>(p)[1];
    dst[0] = a.x; dst[1] = a.y; dst[2] = a.z; dst[3] = a.w;
    dst[4] = b.x; dst[5] = b.y; dst[6] = b.z; dst[7] = b.w;
}

// ---- Phase A: T[b,d,j] = sum_n W[d,n,j,:]·u[b,n,:] ----
// 256 thr = 16 b-groups x 16 j-lanes; 10 register accumulators; 10 atomics.
__global__ __launch_bounds__(256) void caps_T(
    const float* __restrict__ u, const float* __restrict__ W,
    float* __restrict__ T)
{
    const int j = threadIdx.x & 15, b = threadIdx.x >> 4;
    const int n0 = blockIdx.x * NCHA;
    float Tacc[ND];
#pragma unroll
    for (int d = 0; d < ND; ++d) Tacc[d] = 0.f;

    for (int nn = 0; nn < NCHA; ++nn) {
        const int n = n0 + nn;
        float uf[DP];
        load8(u + ((size_t)b * NN + n) * DP, uf);
#pragma unroll
        for (int d = 0; d < ND; ++d) {          // 10 independent load8s
            float wf[DP];
            load8(W + (((size_t)d * NN + n) * DD + j) * DP, wf);
            float s = 0.f;
#pragma unroll
            for (int i = 0; i < DP; ++i) s += wf[i] * uf[i];
            Tacc[d] += s;
        }
    }
#pragma unroll
    for (int d = 0; d < ND; ++d)
        atomicAdd(&T[((size_t)b * ND + d) * DD + j], Tacc[d]);
}

// ---- Phase B: scores -> softmax_d -> S, single W sweep ----
__global__ __launch_bounds__(256) void caps_S(
    const float* __restrict__ u, const float* __restrict__ W,
    const float* __restrict__ Bp, const float* __restrict__ T,
    float* __restrict__ S)
{
    const int j = threadIdx.x & 15, b = threadIdx.x >> 4;
    constexpr float RS8 = 0.35355339059327373f;  // 1/sqrt(8)

    float Treg[ND];                  // T[b,:,j] (L2-hot 10 KB table)
#pragma unroll
    for (int q = 0; q < ND; ++q) Treg[q] = T[((size_t)b * ND + q) * DD + j];

    float Sacc[ND];
#pragma unroll
    for (int q = 0; q < ND; ++q) Sacc[q] = 0.f;

    const int n0 = blockIdx.x * NCHB;
    for (int nn = 0; nn < NCHB; ++nn) {
        const int n = n0 + nn;
        float uf[DP];
        load8(u + ((size_t)b * NN + n) * DP, uf);

        float uh[ND], a[ND];
#pragma unroll
        for (int q = 0; q < ND; ++q) {          // 10 independent load8s
            float wf[DP];
            load8(W + (((size_t)q * NN + n) * DD + j) * DP, wf);
            float s = 0.f;
#pragma unroll
            for (int i = 0; i < DP; ++i) s += wf[i] * uf[i];
            uh[q] = s;
            float v = Treg[q] * s;              // butterfly over the 16 j-lanes
            v += __shfl_xor(v, 8, 16);
            v += __shfl_xor(v, 4, 16);
            v += __shfl_xor(v, 2, 16);
            v += __shfl_xor(v, 1, 16);
            a[q] = v * RS8;
        }
        float m = a[0];
#pragma unroll
        for (int q = 1; q < ND; ++q) m = fmaxf(m, a[q]);
        float e[ND], se = 0.f;
#pragma unroll
        for (int q = 0; q < ND; ++q) { e[q] = expf(a[q] - m); se += e[q]; }
        const float inv_se = 1.f / se;
#pragma unroll
        for (int q = 0; q < ND; ++q)
            Sacc[q] += (Bp[q * NN + n] + e[q] * inv_se) * uh[q];
    }
#pragma unroll
    for (int q = 0; q < ND; ++q)
        atomicAdd(&S[((size_t)b * ND + q) * DD + j], Sacc[q]);
}

// ---- Phase C: squash(S) per (b,d) ----
__global__ __launch_bounds__(256) void caps_out(
    const float* __restrict__ S, float* __restrict__ out)
{
    const int idx = blockIdx.x * 256 + threadIdx.x;   // 2560 total; 16-aligned
    const float Sv = S[idx];                          // groups = (b,d)
    float n2 = Sv * Sv;
#pragma unroll
    for (int off = 8; off >= 1; off >>= 1) n2 += __shfl_xor(n2, off, 16);
    const float nrm = sqrtf(n2);
    const float coef = 1.f - 1.f / (expf(nrm) + 1e-7f);
    out[idx] = Sv * (coef / (nrm + 1e-7f));
}

extern "C" void kernel_launch(void* const* d_in, const int* in_sizes, int n_in,
                              void* d_out, int out_size, void* d_ws, size_t ws_size,
                              hipStream_t stream) {
    const float* u  = nullptr;   // 147456
    const float* W  = nullptr;   // 1474560
    const float* Bp = nullptr;   // 11520
    for (int i = 0; i < n_in; ++i) {
        const int s = in_sizes[i];
        if (s == BN * NN * DP)            u  = (const float*)d_in[i];
        else if (s == ND * NN * DD * DP)  W  = (const float*)d_in[i];
        else if (s == ND * NN)            Bp = (const float*)d_in[i];
    }
    float* out = (float*)d_out;
    float* T = (float*)d_ws;            // 2560 fp32
    float* S = T + BN * ND * DD;        // 2560 fp32 (ws use: 20 KB)

    hipMemsetAsync(d_ws, 0, 2 * BN * ND * DD * sizeof(float), stream);
    caps_T  <<<dim3(NN / NCHA), 256, 0, stream>>>(u, W, T);
    caps_S  <<<dim3(NN / NCHB), 256, 0, stream>>>(u, W, Bp, T, S);
    caps_out<<<dim3(BN * ND * DD / 256), 256, 0, stream>>>(S, out);
}